// Round 8
// baseline (664.245 us; speedup 1.0000x reference)
//
#include <hip/hip_runtime.h>
#include <hip/hip_fp16.h>

#define QN 900
#define CN 91
#define TOTN (QN * CN)   // 81900
#define KSEL 300
#define BN 4
#define OUTW 448
#define MASKPIX (OUTW * OUTW)        // 200704
#define OFFS_LABELS (BN * KSEL)      // 1200
#define OFFS_BOXES  (2 * BN * KSEL)  // 2400
#define OFFS_MASKS  (6 * BN * KSEL)  // 7200
#define MAXC 1024
#define BT 1024
#define NWAVE (BT / 64)
#define MREP 3   // measurement: repeat identical mask work to surface in rocprof top-5

typedef float floatx4 __attribute__((ext_vector_type(4)));

static __device__ __forceinline__ unsigned fkey(float f) {
    unsigned u = __float_as_uint(f);
    return (u & 0x80000000u) ? ~u : (u | 0x80000000u);
}

// ---- selection: radix-select threshold + exact-rank scatter (validated R2/R3/R6) ----
__global__ __launch_bounds__(BT) void select_kernel(
    const float* __restrict__ logits, const float* __restrict__ boxes,
    const int* __restrict__ tsz, float* out, int* qsel)
{
    const int b = blockIdx.x;
    const int tid = threadIdx.x;
    const int wid = tid >> 6;
    const float* lg = logits + (size_t)b * TOTN;

    __shared__ unsigned h16[NWAVE][256];
    __shared__ unsigned hist[256];
    __shared__ int sh_bin, sh_want;
    __shared__ unsigned sh_cnt;
    __shared__ int cidx[MAXC];
    __shared__ unsigned ckey[MAXC];

    for (int i = tid; i < NWAVE * 256; i += BT)
        ((unsigned*)h16)[i] = 0;
    __syncthreads();
    for (int i = tid; i < TOTN; i += BT) {
        unsigned key = fkey(lg[i]);
        atomicAdd(&h16[wid][key >> 24], 1u);
    }
    __syncthreads();
    if (tid < 256) {
        unsigned s = 0;
        for (int w = 0; w < NWAVE; ++w) s += h16[w][tid];
        hist[tid] = s;
    }
    __syncthreads();

    unsigned prefix = 0;
    int want = KSEL;
    for (int round = 0; round < 4; ++round) {
        const int shift = 24 - 8 * round;
        if (round > 0) {
            const unsigned pmask = 0xFFFFFFFFu << (shift + 8);
            if (tid < 256) hist[tid] = 0;
            __syncthreads();
            for (int i = tid; i < TOTN; i += BT) {
                unsigned key = fkey(lg[i]);
                if ((key & pmask) == prefix)
                    atomicAdd(&hist[(key >> shift) & 255u], 1u);
            }
            __syncthreads();
        }
        if (tid == 0) {
            int acc = 0;
            int bin = 255;
            for (; bin > 0; --bin) {
                int c = (int)hist[bin];
                if (acc + c >= want) break;
                acc += c;
            }
            sh_bin = bin;
            sh_want = want - acc;
        }
        __syncthreads();
        prefix |= ((unsigned)sh_bin << shift);
        want = sh_want;
        __syncthreads();
    }
    const unsigned T = prefix;

    if (tid == 0) sh_cnt = 0;
    __syncthreads();
    for (int i = tid; i < TOTN; i += BT) {
        unsigned key = fkey(lg[i]);
        if (key >= T) {
            unsigned pos = atomicAdd(&sh_cnt, 1u);
            if (pos < MAXC) { cidx[pos] = i; ckey[pos] = key; }
        }
    }
    __syncthreads();
    const int ncand = min((int)sh_cnt, MAXC);

    const float fh = (float)tsz[b * 2 + 0];
    const float fw = (float)tsz[b * 2 + 1];

    for (int c = tid; c < ncand; c += BT) {
        const unsigned kc = ckey[c];
        const int ic = cidx[c];
        int rank = 0;
        for (int s = 0; s < ncand; ++s) {
            unsigned ks = ckey[s];
            if (ks > kc || (ks == kc && cidx[s] < ic)) ++rank;
        }
        if (rank < KSEL) {
            float lf = lg[ic];
            float score = 1.0f / (1.0f + expf(-lf));
            int q = ic / CN;
            int label = ic - q * CN;

            out[b * KSEL + rank] = score;
            out[OFFS_LABELS + b * KSEL + rank] = (float)label;

            const float* bx = boxes + ((size_t)b * QN + q) * 4;
            float cx = bx[0], cy = bx[1], ww = bx[2], hh = bx[3];
            float* ob = out + OFFS_BOXES + ((size_t)(b * KSEL + rank)) * 4;
            ob[0] = (cx - 0.5f * ww) * fw;
            ob[1] = (cy - 0.5f * hh) * fh;
            ob[2] = (cx + 0.5f * ww) * fw;
            ob[3] = (cy + 0.5f * hh) * fh;

            qsel[b * KSEL + rank] = q;
        }
    }
}

// ---- mask resize (R6 structure), repeated MREP times for measurement ----
#define SPLIT 4
#define ROWSB (OUTW / SPLIT)   // 112 rows per block

__global__ __launch_bounds__(256) void mask_kernel(
    const float* __restrict__ masks, const int* __restrict__ qsel,
    float* __restrict__ out)
{
    const int mk = blockIdx.x >> 2;
    const int part = blockIdx.x & 3;
    const int b = mk / KSEL;
    const int q = qsel[mk];
    const float* __restrict__ src = masks + ((size_t)b * QN + q) * 784;

    const int j = threadIdx.x & 127;
    const int rhalf = threadIdx.x >> 7;
    if (j >= 112) return;

    const int qd = j & 3;
    const int i4 = j >> 2;
    const int c0 = i4 - 1 + (qd >> 1);
    const int c0c = c0 < 0 ? 0 : c0;
    const int c1c = (c0 + 1 > 27) ? 27 : c0 + 1;
    const float toff = 0.25f * (float)qd - ((qd >= 2) ? 1.0f : 0.0f);
    const float t0 = 0.53125f + toff, t1 = 0.59375f + toff,
                t2 = 0.65625f + toff, t3 = 0.71875f + toff;

    const int ybase0 = part * ROWSB + rhalf;
    float* const obase = out + OFFS_MASKS + (size_t)mk * MASKPIX
                       + (size_t)ybase0 * OUTW + j * 4;

    for (int rep = 0; rep < MREP; ++rep) {
        float* optr = obase;
        float sy = (float)ybase0 * 0.0625f - 0.46875f;
        for (int k = 0; k < ROWSB / 2; ++k) {
            float yf = floorf(sy);
            float ty = sy - yf;
            int iy = (int)yf;
            int y0 = iy < 0 ? 0 : iy;
            int y1 = (iy + 1 > 27) ? 27 : iy + 1;
            const float* r0 = src + y0 * 28;
            const float* r1 = src + y1 * 28;
            float m00 = r0[c0c], m01 = r0[c1c];
            float m10 = r1[c0c], m11 = r1[c1c];
            float v0 = fmaf(ty, m10 - m00, m00);
            float v1 = fmaf(ty, m11 - m01, m01);
            float dv = v1 - v0;
            floatx4 w;
            w.x = fmaf(t0, dv, v0);
            w.y = fmaf(t1, dv, v0);
            w.z = fmaf(t2, dv, v0);
            w.w = fmaf(t3, dv, v0);
            __builtin_nontemporal_store(w, reinterpret_cast<floatx4*>(optr));
            optr += 2 * OUTW;
            sy += 0.125f;
        }
        asm volatile("" ::: "memory");   // keep each rep's stores (no DSE)
    }
}

extern "C" void kernel_launch(void* const* d_in, const int* in_sizes, int n_in,
                              void* d_out, int out_size, void* d_ws, size_t ws_size,
                              hipStream_t stream) {
    const float* pred_logits = (const float*)d_in[0];
    const float* pred_boxes  = (const float*)d_in[1];
    const float* pred_masks  = (const float*)d_in[2];
    const int*   target_sz   = (const int*)d_in[3];
    float* out = (float*)d_out;
    int* qsel = (int*)d_ws;

    select_kernel<<<BN, BT, 0, stream>>>(pred_logits, pred_boxes, target_sz, out, qsel);
    mask_kernel<<<BN * KSEL * SPLIT, 256, 0, stream>>>(pred_masks, qsel, out);
}

// Round 9
// 272.586 us; speedup vs baseline: 2.4368x; 2.4368x over previous
//
#include <hip/hip_runtime.h>
#include <hip/hip_fp16.h>

#define QN 900
#define CN 91
#define TOTN (QN * CN)   // 81900
#define KSEL 300
#define BN 4
#define OUTW 448
#define MASKPIX (OUTW * OUTW)        // 200704
#define OFFS_LABELS (BN * KSEL)      // 1200
#define OFFS_BOXES  (2 * BN * KSEL)  // 2400
#define OFFS_MASKS  (6 * BN * KSEL)  // 7200
#define MAXC 2048
#define BT 1024

typedef float floatx4 __attribute__((ext_vector_type(4)));

static __device__ __forceinline__ unsigned fkey(float f) {
    unsigned u = __float_as_uint(f);
    return (u & 0x80000000u) ? ~u : (u | 0x80000000u);
}

// ---- selection: 2-round radix (16-bit prefix) + gather + exact-rank scatter ----
__global__ __launch_bounds__(BT) void select_kernel(
    const float* __restrict__ logits, const float* __restrict__ boxes,
    const int* __restrict__ tsz, float* out, int* qsel)
{
    const int b = blockIdx.x;
    const int tid = threadIdx.x;
    const int lane = tid & 63;
    const float* lg = logits + (size_t)b * TOTN;

    __shared__ unsigned hlane[256 * 33];   // [bin][lane&31], stride-33 padded
    __shared__ unsigned hist[256];
    __shared__ int sh_bin, sh_want, sh_chunk;
    __shared__ unsigned sh_above, sh_cnt;
    __shared__ int cidx[MAXC];
    __shared__ unsigned ckey[MAXC];

    // ---- round 0: lane-private histogram on top byte (no hot-bin serialization) ----
    for (int i = tid; i < 256 * 33; i += BT) hlane[i] = 0;
    __syncthreads();
    {
        const int sl = lane & 31;
        for (int i = tid; i < TOTN; i += BT) {
            unsigned key = fkey(lg[i]);
            atomicAdd(&hlane[(key >> 24) * 33 + sl], 1u);
        }
    }
    __syncthreads();
    if (tid < 256) {
        unsigned s = 0;
#pragma unroll
        for (int l = 0; l < 32; ++l) s += hlane[tid * 33 + l];
        hist[tid] = s;
    }
    __syncthreads();

    unsigned prefix = 0;
    int want = KSEL;
#pragma unroll
    for (int round = 0; round < 2; ++round) {
        const int shift = 24 - 8 * round;
        if (round > 0) {
            // rebuild hist for second byte among elements matching top byte (~few k)
            if (tid < 256) hist[tid] = 0;
            __syncthreads();
            for (int i = tid; i < TOTN; i += BT) {
                unsigned key = fkey(lg[i]);
                if ((key & 0xFF000000u) == prefix)
                    atomicAdd(&hist[(key >> 16) & 255u], 1u);
            }
            __syncthreads();
        }
        // wave-0 parallel threshold-bin search: 64 chunks of 4 bins
        if (tid < 64) {
            unsigned p = hist[tid * 4] + hist[tid * 4 + 1]
                       + hist[tid * 4 + 2] + hist[tid * 4 + 3];
            unsigned suffix = p;
#pragma unroll
            for (int o = 1; o < 64; o <<= 1) {
                unsigned t = __shfl_down(suffix, o);
                if (tid + o < 64) suffix += t;
            }
            unsigned nxt = __shfl_down(suffix, 1);
            if (tid == 63) nxt = 0;
            bool flag = (suffix >= (unsigned)want) && (nxt < (unsigned)want);
            if (flag) { sh_chunk = tid; sh_above = nxt; }
        }
        __syncthreads();
        if (tid == 0) {
            int ch = sh_chunk;
            unsigned acc = sh_above;
            int j = 3;
            for (; j > 0; --j) {
                if (acc + hist[ch * 4 + j] >= (unsigned)want) break;
                acc += hist[ch * 4 + j];
            }
            sh_bin = ch * 4 + j;
            sh_want = want - (int)acc;
        }
        __syncthreads();
        prefix |= ((unsigned)sh_bin << shift);
        want = sh_want;
        __syncthreads();
    }
    const unsigned T16 = prefix >> 16;

    // ---- gather candidates with key16 >= T16 (~600 expected) ----
    if (tid == 0) sh_cnt = 0;
    __syncthreads();
    for (int i = tid; i < TOTN; i += BT) {
        unsigned key = fkey(lg[i]);
        if ((key >> 16) >= T16) {
            unsigned p = atomicAdd(&sh_cnt, 1u);
            if (p < MAXC) { cidx[p] = i; ckey[p] = key; }
        }
    }
    __syncthreads();
    const int ncand = min((int)sh_cnt, MAXC);

    const float fh = (float)tsz[b * 2 + 0];
    const float fw = (float)tsz[b * 2 + 1];

    // ---- exact rank (desc key, asc index) -> direct scatter ----
    for (int c = tid; c < ncand; c += BT) {
        const unsigned kc = ckey[c];
        const int ic = cidx[c];
        int rank = 0;
        for (int s = 0; s < ncand; ++s) {
            unsigned ks = ckey[s];
            if (ks > kc || (ks == kc && cidx[s] < ic)) ++rank;
        }
        if (rank < KSEL) {
            float lf = lg[ic];
            float score = 1.0f / (1.0f + expf(-lf));
            int q = ic / CN;
            int label = ic - q * CN;

            out[b * KSEL + rank] = score;
            out[OFFS_LABELS + b * KSEL + rank] = (float)label;

            const float* bx = boxes + ((size_t)b * QN + q) * 4;
            float cx = bx[0], cy = bx[1], ww = bx[2], hh = bx[3];
            float* ob = out + OFFS_BOXES + ((size_t)(b * KSEL + rank)) * 4;
            ob[0] = (cx - 0.5f * ww) * fw;
            ob[1] = (cy - 0.5f * hh) * fh;
            ob[2] = (cx + 0.5f * ww) * fw;
            ob[3] = (cy + 0.5f * hh) * fh;

            qsel[b * KSEL + rank] = q;
        }
    }
}

// ---- mask resize: R6 structure, PLAIN stores (nt removed for A/B) ----
#define SPLIT 4
#define ROWSB (OUTW / SPLIT)   // 112 rows per block

__global__ __launch_bounds__(256) void mask_kernel(
    const float* __restrict__ masks, const int* __restrict__ qsel,
    float* __restrict__ out)
{
    const int mk = blockIdx.x >> 2;
    const int part = blockIdx.x & 3;
    const int b = mk / KSEL;
    const int q = qsel[mk];
    const float* __restrict__ src = masks + ((size_t)b * QN + q) * 784;

    const int j = threadIdx.x & 127;
    const int rhalf = threadIdx.x >> 7;
    if (j >= 112) return;

    const int qd = j & 3;
    const int i4 = j >> 2;
    const int c0 = i4 - 1 + (qd >> 1);
    const int c0c = c0 < 0 ? 0 : c0;
    const int c1c = (c0 + 1 > 27) ? 27 : c0 + 1;
    const float toff = 0.25f * (float)qd - ((qd >= 2) ? 1.0f : 0.0f);
    const float t0 = 0.53125f + toff, t1 = 0.59375f + toff,
                t2 = 0.65625f + toff, t3 = 0.71875f + toff;

    const int ybase = part * ROWSB + rhalf;
    float* optr = out + OFFS_MASKS + (size_t)mk * MASKPIX
                + (size_t)ybase * OUTW + j * 4;

    float sy = (float)ybase * 0.0625f - 0.46875f;
    for (int k = 0; k < ROWSB / 2; ++k) {
        float yf = floorf(sy);
        float ty = sy - yf;
        int iy = (int)yf;
        int y0 = iy < 0 ? 0 : iy;
        int y1 = (iy + 1 > 27) ? 27 : iy + 1;
        const float* r0 = src + y0 * 28;
        const float* r1 = src + y1 * 28;
        float m00 = r0[c0c], m01 = r0[c1c];
        float m10 = r1[c0c], m11 = r1[c1c];
        float v0 = fmaf(ty, m10 - m00, m00);
        float v1 = fmaf(ty, m11 - m01, m01);
        float dv = v1 - v0;
        floatx4 w;
        w.x = fmaf(t0, dv, v0);
        w.y = fmaf(t1, dv, v0);
        w.z = fmaf(t2, dv, v0);
        w.w = fmaf(t3, dv, v0);
        *reinterpret_cast<floatx4*>(optr) = w;   // plain store (A/B vs nt)
        optr += 2 * OUTW;
        sy += 0.125f;
    }
}

extern "C" void kernel_launch(void* const* d_in, const int* in_sizes, int n_in,
                              void* d_out, int out_size, void* d_ws, size_t ws_size,
                              hipStream_t stream) {
    const float* pred_logits = (const float*)d_in[0];
    const float* pred_boxes  = (const float*)d_in[1];
    const float* pred_masks  = (const float*)d_in[2];
    const int*   target_sz   = (const int*)d_in[3];
    float* out = (float*)d_out;
    int* qsel = (int*)d_ws;

    select_kernel<<<BN, BT, 0, stream>>>(pred_logits, pred_boxes, target_sz, out, qsel);
    mask_kernel<<<BN * KSEL * SPLIT, 256, 0, stream>>>(pred_masks, qsel, out);
}